// Round 5
// baseline (223.414 us; speedup 1.0000x reference)
//
#include <hip/hip_runtime.h>

// Problem constants (T=512, B=16 -> 8192 tokens), all tensors float32
#define NTOK 8192
#define CDIM 512
#define NB   8
#define RD   64
#define OD   512
#define XROW 516             // x row pitch in LDS (f32): 16B-aligned, conflict-free

typedef unsigned char  u8;
typedef unsigned int   u32;
typedef unsigned short u16;

// workspace layout (bytes)
#define WS_Q      0          // 8192 u8
#define WS_COUNTS 8192       // 256 u32
#define WS_CURSOR 9216       // 256 u32
#define WS_OFF    10240      // 257 u32
#define WS_LIST   11520      // 8192 u16
#define WS_V      28672      // 8192*64 f32 (16B aligned)
#define WS_NEED   (WS_V + NTOK * RD * 4)

// ---------------------------------------------------------------------------
// init: zero the per-code counters (ws is poisoned 0xAA before every launch)
// ---------------------------------------------------------------------------
__global__ __launch_bounds__(256) void kInit(u32* __restrict__ counts) {
    counts[threadIdx.x] = 0u;
}

// ---------------------------------------------------------------------------
// Phase A: 512 blocks x 256 threads, 16 tokens/block. LDS 33 KB -> 4 blk/CU.
//  all threads: stage x tile (16 x 512 f32, coalesced) into LDS
//  waves 0-1 : v = pw_w1 @ x. wave w owns tokens w*8..w*8+7, lane = w1 row.
//              x read via wave-uniform (scalar-path) global loads; w1 via
//              per-lane float4 (L1/L2-hot). FMA-bound, no LDS in loop.
//  waves 2-3 : logits from LDS, f64 accumulation (bit = sign(k)).
//              thread = (token, bit); ballot -> code byte; atomic counts.
// ---------------------------------------------------------------------------
__global__ __launch_bounds__(256) void kA(
    const float* __restrict__ x, const float* __restrict__ map_w,
    const float* __restrict__ map_b, const float* __restrict__ w1,
    u8* __restrict__ q_out, float* __restrict__ v_out,
    u32* __restrict__ counts, float* __restrict__ loss_out)
{
    const int t    = threadIdx.x;
    const int tok0 = blockIdx.x * 16;
    __shared__ float xs[16 * XROW];

    // ---- stage x tile (coalesced float4; padded 16B-aligned rows) ----
    const float4* __restrict__ xsrc = (const float4*)(x + (size_t)tok0 * CDIM);
    #pragma unroll
    for (int u = 0; u < 8; ++u) {
        int i = u * 256 + t;
        int r = i >> 7, c = i & 127;                  // CDIM/4 = 128
        *(float4*)(xs + r * XROW + c * 4) = xsrc[i];
    }
    __syncthreads();

    const int wvu  = __builtin_amdgcn_readfirstlane(t >> 6);  // uniform wave id
    const int lane = t & 63;

    if (wvu < 2) {
        // ---- v-limb: 8 tokens per wave, lane = w1 row ----
        const int tb = tok0 + wvu * 8;                // wave-uniform token base
        const float4* __restrict__ w4  = (const float4*)w1 + (size_t)lane * 128;
        const float4* __restrict__ xg  = (const float4*)x + (size_t)tb * 128;
        float a0=0.f,a1=0.f,a2=0.f,a3=0.f,a4=0.f,a5=0.f,a6=0.f,a7=0.f;
        for (int k = 0; k < 128; ++k) {
            float4 w = w4[k];
            float4 x0 = xg[0*128+k], x1 = xg[1*128+k], x2 = xg[2*128+k], x3 = xg[3*128+k];
            float4 x4v = xg[4*128+k], x5 = xg[5*128+k], x6 = xg[6*128+k], x7 = xg[7*128+k];
            a0 += w.x*x0.x + w.y*x0.y + w.z*x0.z + w.w*x0.w;
            a1 += w.x*x1.x + w.y*x1.y + w.z*x1.z + w.w*x1.w;
            a2 += w.x*x2.x + w.y*x2.y + w.z*x2.z + w.w*x2.w;
            a3 += w.x*x3.x + w.y*x3.y + w.z*x3.z + w.w*x3.w;
            a4 += w.x*x4v.x + w.y*x4v.y + w.z*x4v.z + w.w*x4v.w;
            a5 += w.x*x5.x + w.y*x5.y + w.z*x5.z + w.w*x5.w;
            a6 += w.x*x6.x + w.y*x6.y + w.z*x6.z + w.w*x6.w;
            a7 += w.x*x7.x + w.y*x7.y + w.z*x7.z + w.w*x7.w;
        }
        v_out[(size_t)(tb+0) * RD + lane] = a0;
        v_out[(size_t)(tb+1) * RD + lane] = a1;
        v_out[(size_t)(tb+2) * RD + lane] = a2;
        v_out[(size_t)(tb+3) * RD + lane] = a3;
        v_out[(size_t)(tb+4) * RD + lane] = a4;
        v_out[(size_t)(tb+5) * RD + lane] = a5;
        v_out[(size_t)(tb+6) * RD + lane] = a6;
        v_out[(size_t)(tb+7) * RD + lane] = a7;
    } else {
        // ---- logit limb: thread = (token tk, bit), f64 (sign-critical) ----
        const int lt  = t - 128;                      // 0..127
        const int tk  = lt >> 3;                      // 0..15
        const int bit = lt & 7;
        const float4* __restrict__ m4 = (const float4*)map_w + (size_t)bit * 128;
        const float4* __restrict__ xl = (const float4*)(xs + tk * XROW);
        double s = 0.0;
        for (int k = 0; k < 128; ++k) {
            float4 m = m4[k], xv = xl[k];
            s += (double)m.x * (double)xv.x + (double)m.y * (double)xv.y
               + (double)m.z * (double)xv.z + (double)m.w * (double)xv.w;
        }
        s += (double)map_b[bit];
        unsigned long long mask = __ballot(s > 0.0);  // lane = (tk&7)*8 + bit
        if (bit == 0) {
            u32 qv = (u32)((mask >> ((tk & 7) * 8)) & 0xFFull);
            q_out[tok0 + tk] = (u8)qv;
            atomicAdd(&counts[qv], 1u);
        }
    }
    if (blockIdx.x == 0 && t == 0) loss_out[0] = 0.0f;   // loss output = 0
}

// ---------------------------------------------------------------------------
// prefix: exclusive scan of counts -> off[0..256], cursor = off
// ---------------------------------------------------------------------------
__global__ __launch_bounds__(256) void kPrefix(
    const u32* __restrict__ counts, u32* __restrict__ off, u32* __restrict__ cursor)
{
    __shared__ u32 s[256];
    const int t = threadIdx.x;
    u32 c = counts[t];
    s[t] = c;
    __syncthreads();
    for (int d = 1; d < 256; d <<= 1) {
        u32 v = (t >= d) ? s[t - d] : 0u;
        __syncthreads();
        s[t] += v;
        __syncthreads();
    }
    u32 excl = s[t] - c;
    off[t] = excl;
    cursor[t] = excl;
    if (t == 255) off[256] = s[255];
}

// ---------------------------------------------------------------------------
// scatter: tokens into per-code contiguous lists
// ---------------------------------------------------------------------------
__global__ __launch_bounds__(256) void kScatter(
    const u8* __restrict__ q_arr, u32* __restrict__ cursor, u16* __restrict__ list)
{
    const int tok = blockIdx.x * 256 + threadIdx.x;
    u32 pos = atomicAdd(&cursor[q_arr[tok]], 1u);
    list[pos] = (u16)tok;
}

// ---------------------------------------------------------------------------
// Phase B: 1024 blocks x 256 threads. block = (q = b>>2, output-half, token-
// half). Thread owns output o: fused weights in 64 VGPRs; bucket list staged
// in LDS; 4 tokens/iteration with independent accumulators (ILP-4 over the
// uniform v-row loads); coalesced y stores.
// ---------------------------------------------------------------------------
__global__ __launch_bounds__(256) void kB(
    const u16* __restrict__ list, const u32* __restrict__ off,
    const float* __restrict__ v_arr,
    const float* __restrict__ w21, const float* __restrict__ w22,
    const float* __restrict__ pwB, float* __restrict__ y)
{
    const int q  = blockIdx.x >> 2;
    const int oh = (blockIdx.x >> 1) & 1;
    const int th = blockIdx.x & 1;
    const int t  = threadIdx.x;
    const int o  = oh * 256 + t;

    const u32 lo = off[q], hi = off[q + 1];
    const int n = (int)(hi - lo);
    if (n == 0) return;
    const int half = (n + 1) >> 1;
    const int s0   = th * half;
    const int cnt  = min(n - s0, half);
    if (cnt <= 0) return;                         // uniform exit

    __shared__ u16 ltok[4096];                    // 8 KB (half-list max)
    for (int i = t; i < cnt; i += 256) ltok[i] = list[lo + s0 + i];

    // fused weight row for output o (64 f32 in VGPRs, coalesced float4)
    const float4* __restrict__ pa = (const float4*)(w21 + ((size_t)q * OD + o) * RD);
    const float4* __restrict__ pb = (const float4*)(w22 + ((size_t)(255 - q) * OD + o) * RD);
    float4 w[16];
    #pragma unroll
    for (int j = 0; j < 16; ++j) {
        float4 a = pa[j], b = pb[j];
        w[j] = make_float4(a.x + b.x, a.y + b.y, a.z + b.z, a.w + b.w);
    }
    const float bias = pwB[o];
    __syncthreads();

    const float4* __restrict__ v4 = (const float4*)v_arr;
    for (int i = 0; i < cnt; i += 4) {
        const int nb = cnt - i;
        const int i1 = (nb > 1) ? i + 1 : i;
        const int i2 = (nb > 2) ? i + 2 : i;
        const int i3 = (nb > 3) ? i + 3 : i;
        const int t0 = __builtin_amdgcn_readfirstlane((int)ltok[i]);
        const int t1 = __builtin_amdgcn_readfirstlane((int)ltok[i1]);
        const int t2 = __builtin_amdgcn_readfirstlane((int)ltok[i2]);
        const int t3 = __builtin_amdgcn_readfirstlane((int)ltok[i3]);
        const float4* __restrict__ p0 = v4 + (size_t)t0 * 16;
        const float4* __restrict__ p1 = v4 + (size_t)t1 * 16;
        const float4* __restrict__ p2 = v4 + (size_t)t2 * 16;
        const float4* __restrict__ p3 = v4 + (size_t)t3 * 16;
        float a0 = bias, a1 = bias, a2 = bias, a3 = bias;
        #pragma unroll
        for (int j = 0; j < 16; ++j) {
            float4 ww = w[j];
            float4 v0 = p0[j]; a0 += ww.x*v0.x + ww.y*v0.y + ww.z*v0.z + ww.w*v0.w;
            float4 v1 = p1[j]; a1 += ww.x*v1.x + ww.y*v1.y + ww.z*v1.z + ww.w*v1.w;
            float4 v2 = p2[j]; a2 += ww.x*v2.x + ww.y*v2.y + ww.z*v2.z + ww.w*v2.w;
            float4 v3 = p3[j]; a3 += ww.x*v3.x + ww.y*v3.y + ww.z*v3.z + ww.w*v3.w;
        }
        y[(size_t)t0 * OD + o] = a0;
        if (nb > 1) y[(size_t)t1 * OD + o] = a1;
        if (nb > 2) y[(size_t)t2 * OD + o] = a2;
        if (nb > 3) y[(size_t)t3 * OD + o] = a3;
    }
}

// ---------------------------------------------------------------------------
// Fallback (ws too small): workspace-free, one block per token.
// ---------------------------------------------------------------------------
__global__ __launch_bounds__(256) void mono(
    const float* __restrict__ x, const float* __restrict__ map_w,
    const float* __restrict__ map_b, const float* __restrict__ w1,
    const float* __restrict__ w21, const float* __restrict__ w22,
    const float* __restrict__ pwB, float* __restrict__ y)
{
    const int tok = blockIdx.x;
    const int t   = threadIdx.x;
    __shared__ float xsh[CDIM];
    __shared__ float vsh[RD];
    __shared__ int qsh;

    if (t == 0) qsh = 0;
    for (int i = t; i < CDIM; i += 256) xsh[i] = x[(size_t)tok * CDIM + i];
    __syncthreads();

    if (t < NB) {
        double a = 0.0;
        const float* mrow = map_w + (size_t)t * CDIM;
        for (int j = 0; j < CDIM; ++j) a += (double)mrow[j] * (double)xsh[j];
        a += (double)map_b[t];
        if (a > 0.0) atomicOr(&qsh, 1 << t);
    }
    if (t < RD) {
        const float* wrow = w1 + (size_t)t * CDIM;
        float acc = 0.f;
        for (int j = 0; j < CDIM; ++j) acc += wrow[j] * xsh[j];
        vsh[t] = acc;
    }
    __syncthreads();

    const int q = qsh;
    for (int o = t; o < OD; o += 256) {
        const float* pa = w21 + (size_t)q * (OD * RD) + (size_t)o * RD;
        const float* pb = w22 + (size_t)(255 - q) * (OD * RD) + (size_t)o * RD;
        float acc = pwB[o];
        for (int r = 0; r < RD; ++r) acc += (pa[r] + pb[r]) * vsh[r];
        y[(size_t)tok * OD + o] = acc;
    }
    if (tok == 0 && t == 0) y[(size_t)NTOK * OD] = 0.0f;
}

extern "C" void kernel_launch(void* const* d_in, const int* in_sizes, int n_in,
                              void* d_out, int out_size, void* d_ws, size_t ws_size,
                              hipStream_t stream) {
    const float* x     = (const float*)d_in[0];
    // d_in[1] = key: unused by the forward pass
    const float* map_w = (const float*)d_in[2];
    const float* map_b = (const float*)d_in[3];
    const float* w1    = (const float*)d_in[4];
    const float* w21   = (const float*)d_in[5];
    const float* w22   = (const float*)d_in[6];
    const float* pwB   = (const float*)d_in[7];
    float* out = (float*)d_out;

    if (ws_size >= (size_t)WS_NEED) {
        char* ws = (char*)d_ws;
        u8*    q_ws   = (u8*)(ws + WS_Q);
        u32*   counts = (u32*)(ws + WS_COUNTS);
        u32*   cursor = (u32*)(ws + WS_CURSOR);
        u32*   off    = (u32*)(ws + WS_OFF);
        u16*   list   = (u16*)(ws + WS_LIST);
        float* v_ws   = (float*)(ws + WS_V);

        kInit<<<1, 256, 0, stream>>>(counts);
        kA<<<NTOK / 16, 256, 0, stream>>>(x, map_w, map_b, w1, q_ws, v_ws, counts,
                                          out + (size_t)NTOK * OD);
        kPrefix<<<1, 256, 0, stream>>>(counts, off, cursor);
        kScatter<<<NTOK / 256, 256, 0, stream>>>(q_ws, cursor, list);
        kB<<<1024, 256, 0, stream>>>(list, off, v_ws, w21, w22, pwB, out);
    } else {
        mono<<<NTOK, 256, 0, stream>>>(x, map_w, map_b, w1, w21, w22, pwB, out);
    }
}